// Round 17
// baseline (108.477 us; speedup 1.0000x reference)
//
#include <hip/hip_runtime.h>
#include <math.h>

#define BATCH 128
#define NPWM 512
#define LEN 1000
#define NEXT 1024     // 2*NPWM (fwd + revcomp interleaved: f_ext = 2*f + strand)
#define KSLOT 96      // kk padded 19->24, slot = kk*4 + c (16x16x32: K mult of 32)

typedef __bf16 bf16x4 __attribute__((ext_vector_type(4)));
typedef __bf16 bf16x8 __attribute__((ext_vector_type(8)));
typedef float  f32x4  __attribute__((ext_vector_type(4)));

#define MFMA16(a, b, c) __builtin_amdgcn_mfma_f32_16x16x32_bf16(a, b, c, 0, 0, 0)

// ---- prepack W: (512,4,19) fp32 -> (1024,96) bf16 hi/lo, zeros at pad slots ----
__global__ __launch_bounds__(256)
void prepack_w(const float* __restrict__ w, __bf16* __restrict__ whi, __bf16* __restrict__ wlo)
{
    int idx = blockIdx.x * 256 + threadIdx.x;
    if (idx >= NEXT * KSLOT) return;
    int fe = idx / KSLOT;
    int t  = idx - fe * KSLOT;
    int kk = t >> 2;
    int c  = t & 3;
    int f      = fe >> 1;
    int strand = fe & 1;
    float v = 0.0f;
    if (kk < 19)
        v = strand ? w[f*76 + (3-c)*19 + (18-kk)]   // reverse-complement
                   : w[f*76 + c*19 + kk];
    __bf16 h = (__bf16)v;
    whi[idx] = h;
    wlo[idx] = (__bf16)(v - (float)h);
}

// ---- main: R16 inner loop at 8 waves/SIMD. block = 512 thr = 8 waves =
// 4 filter-tiles(32 f_ext) x 2 position-halves; grid = (128,8) = 4 blocks/CU
// -> 32 waves/CU (hardware max). VGPR <=64 class (launch_bounds(512,8)).
// Per iter: 5 shared b128 B-frags feed 20 MFMAs in 4 indep dep-5 chains;
// s=2 chunk (taps 16-18+pad) hi-term only (error ~0.007 abs, R16-validated).
__global__ __launch_bounds__(512, 8)
void pwm_mfma(const float* __restrict__ x,
              const __bf16* __restrict__ whi,
              const __bf16* __restrict__ wlo,
              float* __restrict__ out)
{
    __shared__ __align__(16) __bf16 S[8256];   // H0 @0, H1 (shifted +1 pos) @4128
    __shared__ float red[2][128];

    const int tid   = threadIdx.x;
    const int b     = blockIdx.x;
    const int ftile = blockIdx.y;   // 0..7 (128 f_ext per block)
    const int lane  = tid & 63;
    const int wave  = tid >> 6;     // 0..7
    const int wp    = wave & 1;     // position half
    const int ft32  = wave >> 1;    // which 32-f_ext tile (0..3)
    const int row   = lane & 15;    // position within 16-tile / W k-row
    const int g     = lane >> 4;    // k-eighth group (0..3)

    __bf16* H0 = S;
    __bf16* H1 = S + 4128;          // +32-elem skew: odd-parity banks offset (<=3-way)

    // stage bf16(x[b]) position-major [pos][c] + shifted copy (single pass)
    for (int i = tid; i < 1024; i += 512) {
        bf16x4 hv;
        #pragma unroll
        for (int c = 0; c < 4; ++c) {
            float v = (i < LEN) ? x[(size_t)b*4000 + c*1000 + i] : 0.0f;
            hv[c] = (__bf16)v;
        }
        *(bf16x4*)(H0 + i*4) = hv;
        if (i > 0) *(bf16x4*)(H1 + (i-1)*4) = hv;
    }
    if (tid == 0) { bf16x4 z = {}; *(bf16x4*)(H1 + 1023*4) = z; }

    // A fragments (W hi/lo) -> regs: lane holds W[f0+fg*16+row][k = s*32 + g*8 + j]
    bf16x8 wah[2][3], wal[2][2];   // wal[.][2] unused (s=2 trim)
    {
        const int f0 = ftile*128 + ft32*32;
        #pragma unroll
        for (int fg = 0; fg < 2; ++fg) {
            #pragma unroll
            for (int s = 0; s < 3; ++s) {
                const size_t o = (size_t)(f0 + fg*16 + row)*KSLOT + s*32 + g*8;
                wah[fg][s] = *(const bf16x8*)(whi + o);
                if (s < 2) wal[fg][s] = *(const bf16x8*)(wlo + o);
            }
        }
    }
    __syncthreads();

    // B base: pos-tile0 pos = it*32 + row; parity(row) loop-invariant -> 16B reads
    const int lp   = row + 2*g;
    const int par  = row & 1;
    const __bf16* bp = par ? H1 : H0;
    const int eoff = lp*4 - (par ? 4 : 0);

    float m0[4], m1[4];
    #pragma unroll
    for (int r = 0; r < 4; ++r) { m0[r] = -INFINITY; m1[r] = -INFINITY; }
    const f32x4 zc = {};

    const int it_beg = wp ? 16 : 0;
    const int it_end = wp ? 31 : 16;
    for (int it = it_beg; it < it_end; ++it) {
        const int ibase = it*128 + eoff;
        bf16x8 g0 = *(const bf16x8*)(bp + ibase);
        bf16x8 g1 = *(const bf16x8*)(bp + ibase + 32);
        bf16x8 g2 = *(const bf16x8*)(bp + ibase + 64);   // shared: tile0 s2 / tile1 s0
        bf16x8 g3 = *(const bf16x8*)(bp + ibase + 96);
        bf16x8 g4 = *(const bf16x8*)(bp + ibase + 128);

        // 4 independent dep-5 chains (2 filter-tiles x 2 pos-tiles), 20 MFMAs
        f32x4 a00 = MFMA16(wah[0][0], g0, zc);
        f32x4 a10 = MFMA16(wah[1][0], g0, zc);
        f32x4 a01 = MFMA16(wah[0][0], g2, zc);
        f32x4 a11 = MFMA16(wah[1][0], g2, zc);
        a00 = MFMA16(wal[0][0], g0, a00);
        a10 = MFMA16(wal[1][0], g0, a10);
        a01 = MFMA16(wal[0][0], g2, a01);
        a11 = MFMA16(wal[1][0], g2, a11);
        a00 = MFMA16(wah[0][1], g1, a00);
        a10 = MFMA16(wah[1][1], g1, a10);
        a01 = MFMA16(wah[0][1], g3, a01);
        a11 = MFMA16(wah[1][1], g3, a11);
        a00 = MFMA16(wal[0][1], g1, a00);
        a10 = MFMA16(wal[1][1], g1, a10);
        a01 = MFMA16(wal[0][1], g3, a01);
        a11 = MFMA16(wal[1][1], g3, a11);
        a00 = MFMA16(wah[0][2], g2, a00);   // s=2: hi-term only
        a10 = MFMA16(wah[1][2], g2, a10);
        a01 = MFMA16(wah[0][2], g4, a01);
        a11 = MFMA16(wah[1][2], g4, a11);

        if (it == 30 && row >= 6) {   // tile1 pos = 976+row >= 982: exclude
            #pragma unroll
            for (int r = 0; r < 4; ++r) { a01[r] = -INFINITY; a11[r] = -INFINITY; }
        }
        #pragma unroll
        for (int r = 0; r < 4; ++r) {
            m0[r] = fmaxf(m0[r], fmaxf(a00[r], a01[r]));
            m1[r] = fmaxf(m1[r], fmaxf(a10[r], a11[r]));
        }
    }

    // reduce over the 16 position-columns (lane&15)
    #pragma unroll
    for (int off = 1; off < 16; off <<= 1)
        #pragma unroll
        for (int r = 0; r < 4; ++r) {
            m0[r] = fmaxf(m0[r], __shfl_xor(m0[r], off, 64));
            m1[r] = fmaxf(m1[r], __shfl_xor(m1[r], off, 64));
        }

    // D row (filter within 16-tile) = g*4 + r
    if (row == 0) {
        #pragma unroll
        for (int r = 0; r < 4; ++r) {
            red[wp][ft32*32 +      g*4 + r] = m0[r];
            red[wp][ft32*32 + 16 + g*4 + r] = m1[r];
        }
    }
    __syncthreads();
    if (tid < 64) {   // combine strand pairs (f_ext = 2f, 2f+1) and position halves
        float v0 = fmaxf(red[0][2*tid], red[0][2*tid+1]);
        float v1 = fmaxf(red[1][2*tid], red[1][2*tid+1]);
        out[(size_t)b*NPWM + ftile*64 + tid] = fmaxf(v0, v1);
    }
}

extern "C" void kernel_launch(void* const* d_in, const int* in_sizes, int n_in,
                              void* d_out, int out_size, void* d_ws, size_t ws_size,
                              hipStream_t stream)
{
    const float* x = (const float*)d_in[0];   // (128, 4, 1000)
    const float* w = (const float*)d_in[1];   // (512, 4, 19)
    float* out = (float*)d_out;               // (128, 512)

    __bf16* whi = (__bf16*)d_ws;              // 1024*96 bf16
    __bf16* wlo = whi + NEXT*KSLOT;

    prepack_w<<<dim3((NEXT*KSLOT + 255)/256), 256, 0, stream>>>(w, whi, wlo);
    pwm_mfma<<<dim3(BATCH, 8), 512, 0, stream>>>(x, whi, wlo, out);
}

// Round 18
// 40.061 us; speedup vs baseline: 2.7078x; 2.7078x over previous
//
#include <hip/hip_runtime.h>
#include <math.h>

#define BATCH 128
#define NPWM 512
#define LEN 1000
#define NEXT 1024     // 2*NPWM (fwd + revcomp interleaved: f_ext = 2*f + strand)
#define KSLOT 96      // kk padded 19->24, slot = kk*4 + c (16x16x32: K mult of 32)

typedef __bf16 bf16x4 __attribute__((ext_vector_type(4)));
typedef __bf16 bf16x8 __attribute__((ext_vector_type(8)));
typedef float  f32x4  __attribute__((ext_vector_type(4)));

#define MFMA16(a, b, c) __builtin_amdgcn_mfma_f32_16x16x32_bf16(a, b, c, 0, 0, 0)

// ---- prepack W: (512,4,19) fp32 -> (1024,96) bf16 hi/lo, zeros at pad slots ----
__global__ __launch_bounds__(256)
void prepack_w(const float* __restrict__ w, __bf16* __restrict__ whi, __bf16* __restrict__ wlo)
{
    int idx = blockIdx.x * 256 + threadIdx.x;
    if (idx >= NEXT * KSLOT) return;
    int fe = idx / KSLOT;
    int t  = idx - fe * KSLOT;
    int kk = t >> 2;
    int c  = t & 3;
    int f      = fe >> 1;
    int strand = fe & 1;
    float v = 0.0f;
    if (kk < 19)
        v = strand ? w[f*76 + (3-c)*19 + (18-kk)]   // reverse-complement
                   : w[f*76 + c*19 + kk];
    __bf16 h = (__bf16)v;
    whi[idx] = h;
    wlo[idx] = (__bf16)(v - (float)h);
}

// ---- main: R16 inner loop at 512 thr/block for TLP. block = 8 waves =
// 4 filter-tiles(32 f_ext) x 2 position-halves; grid = (128,8) = 4 blocks/CU
// -> 32 waves/CU if VGPR <= 64 (natural allocation ~56; NO min-waves arg --
// hipcc's cap formula at B=512 with an explicit arg forced a 32-reg spill in
// R17). Per iter: 5 shared b128 B-frags feed 20 MFMAs in 4 indep dep-5 chains;
// s=2 chunk (taps 16-18+pad) hi-term only (error ~0.007 abs, R16-validated).
__global__ __launch_bounds__(512)
void pwm_mfma(const float* __restrict__ x,
              const __bf16* __restrict__ whi,
              const __bf16* __restrict__ wlo,
              float* __restrict__ out)
{
    __shared__ __align__(16) __bf16 S[8256];   // H0 @0, H1 (shifted +1 pos) @4128
    __shared__ float red[2][128];

    const int tid   = threadIdx.x;
    const int b     = blockIdx.x;
    const int ftile = blockIdx.y;   // 0..7 (128 f_ext per block)
    const int lane  = tid & 63;
    const int wave  = tid >> 6;     // 0..7
    const int wp    = wave & 1;     // position half
    const int ft32  = wave >> 1;    // which 32-f_ext tile (0..3)
    const int row   = lane & 15;    // position within 16-tile / W k-row
    const int g     = lane >> 4;    // k-eighth group (0..3)

    __bf16* H0 = S;
    __bf16* H1 = S + 4128;          // +32-elem skew: odd-parity banks offset (<=3-way)

    // stage bf16(x[b]) position-major [pos][c] + shifted copy (single pass)
    for (int i = tid; i < 1024; i += 512) {
        bf16x4 hv;
        #pragma unroll
        for (int c = 0; c < 4; ++c) {
            float v = (i < LEN) ? x[(size_t)b*4000 + c*1000 + i] : 0.0f;
            hv[c] = (__bf16)v;
        }
        *(bf16x4*)(H0 + i*4) = hv;
        if (i > 0) *(bf16x4*)(H1 + (i-1)*4) = hv;
    }
    if (tid == 0) { bf16x4 z = {}; *(bf16x4*)(H1 + 1023*4) = z; }

    // A fragments (W hi/lo) -> regs: lane holds W[f0+fg*16+row][k = s*32 + g*8 + j]
    bf16x8 wah[2][3], wal[2][2];   // wal[.][2] unused (s=2 trim)
    {
        const int f0 = ftile*128 + ft32*32;
        #pragma unroll
        for (int fg = 0; fg < 2; ++fg) {
            #pragma unroll
            for (int s = 0; s < 3; ++s) {
                const size_t o = (size_t)(f0 + fg*16 + row)*KSLOT + s*32 + g*8;
                wah[fg][s] = *(const bf16x8*)(whi + o);
                if (s < 2) wal[fg][s] = *(const bf16x8*)(wlo + o);
            }
        }
    }
    __syncthreads();

    // B base: pos-tile0 pos = it*32 + row; parity(row) loop-invariant -> 16B reads
    const int lp   = row + 2*g;
    const int par  = row & 1;
    const __bf16* bp = par ? H1 : H0;
    const int eoff = lp*4 - (par ? 4 : 0);

    float m0[4], m1[4];
    #pragma unroll
    for (int r = 0; r < 4; ++r) { m0[r] = -INFINITY; m1[r] = -INFINITY; }
    const f32x4 zc = {};

    const int it_beg = wp ? 16 : 0;
    const int it_end = wp ? 31 : 16;
    for (int it = it_beg; it < it_end; ++it) {
        const int ibase = it*128 + eoff;
        bf16x8 g0 = *(const bf16x8*)(bp + ibase);
        bf16x8 g1 = *(const bf16x8*)(bp + ibase + 32);
        bf16x8 g2 = *(const bf16x8*)(bp + ibase + 64);   // shared: tile0 s2 / tile1 s0
        bf16x8 g3 = *(const bf16x8*)(bp + ibase + 96);
        bf16x8 g4 = *(const bf16x8*)(bp + ibase + 128);

        // 4 independent dep-5 chains (2 filter-tiles x 2 pos-tiles), 20 MFMAs
        f32x4 a00 = MFMA16(wah[0][0], g0, zc);
        f32x4 a10 = MFMA16(wah[1][0], g0, zc);
        f32x4 a01 = MFMA16(wah[0][0], g2, zc);
        f32x4 a11 = MFMA16(wah[1][0], g2, zc);
        a00 = MFMA16(wal[0][0], g0, a00);
        a10 = MFMA16(wal[1][0], g0, a10);
        a01 = MFMA16(wal[0][0], g2, a01);
        a11 = MFMA16(wal[1][0], g2, a11);
        a00 = MFMA16(wah[0][1], g1, a00);
        a10 = MFMA16(wah[1][1], g1, a10);
        a01 = MFMA16(wah[0][1], g3, a01);
        a11 = MFMA16(wah[1][1], g3, a11);
        a00 = MFMA16(wal[0][1], g1, a00);
        a10 = MFMA16(wal[1][1], g1, a10);
        a01 = MFMA16(wal[0][1], g3, a01);
        a11 = MFMA16(wal[1][1], g3, a11);
        a00 = MFMA16(wah[0][2], g2, a00);   // s=2: hi-term only
        a10 = MFMA16(wah[1][2], g2, a10);
        a01 = MFMA16(wah[0][2], g4, a01);
        a11 = MFMA16(wah[1][2], g4, a11);

        if (it == 30 && row >= 6) {   // tile1 pos = 976+row >= 982: exclude
            #pragma unroll
            for (int r = 0; r < 4; ++r) { a01[r] = -INFINITY; a11[r] = -INFINITY; }
        }
        #pragma unroll
        for (int r = 0; r < 4; ++r) {
            m0[r] = fmaxf(m0[r], fmaxf(a00[r], a01[r]));
            m1[r] = fmaxf(m1[r], fmaxf(a10[r], a11[r]));
        }
    }

    // reduce over the 16 position-columns (lane&15)
    #pragma unroll
    for (int off = 1; off < 16; off <<= 1)
        #pragma unroll
        for (int r = 0; r < 4; ++r) {
            m0[r] = fmaxf(m0[r], __shfl_xor(m0[r], off, 64));
            m1[r] = fmaxf(m1[r], __shfl_xor(m1[r], off, 64));
        }

    // D row (filter within 16-tile) = g*4 + r
    if (row == 0) {
        #pragma unroll
        for (int r = 0; r < 4; ++r) {
            red[wp][ft32*32 +      g*4 + r] = m0[r];
            red[wp][ft32*32 + 16 + g*4 + r] = m1[r];
        }
    }
    __syncthreads();
    if (tid < 64) {   // combine strand pairs (f_ext = 2f, 2f+1) and position halves
        float v0 = fmaxf(red[0][2*tid], red[0][2*tid+1]);
        float v1 = fmaxf(red[1][2*tid], red[1][2*tid+1]);
        out[(size_t)b*NPWM + ftile*64 + tid] = fmaxf(v0, v1);
    }
}

extern "C" void kernel_launch(void* const* d_in, const int* in_sizes, int n_in,
                              void* d_out, int out_size, void* d_ws, size_t ws_size,
                              hipStream_t stream)
{
    const float* x = (const float*)d_in[0];   // (128, 4, 1000)
    const float* w = (const float*)d_in[1];   // (512, 4, 19)
    float* out = (float*)d_out;               // (128, 512)

    __bf16* whi = (__bf16*)d_ws;              // 1024*96 bf16
    __bf16* wlo = whi + NEXT*KSLOT;

    prepack_w<<<dim3((NEXT*KSLOT + 255)/256), 256, 0, stream>>>(w, whi, wlo);
    pwm_mfma<<<dim3(BATCH, 8), 512, 0, stream>>>(x, whi, wlo, out);
}

// Round 19
// 33.527 us; speedup vs baseline: 3.2355x; 1.1949x over previous
//
#include <hip/hip_runtime.h>
#include <math.h>

#define BATCH 128
#define NPWM 512
#define LEN 1000
#define NEXT 1024     // 2*NPWM (fwd + revcomp interleaved: f_ext = 2*f + strand)
#define KSLOT 96      // kk padded 19->24, slot = kk*4 + c (16x16x32: K mult of 32)

typedef _Float16 f16x4 __attribute__((ext_vector_type(4)));
typedef _Float16 f16x8 __attribute__((ext_vector_type(8)));
typedef float    f32x4 __attribute__((ext_vector_type(4)));

#define MFMA16(a, b, c) __builtin_amdgcn_mfma_f32_16x16x32_f16(a, b, c, 0, 0, 0)

// ---- prepack W: (512,4,19) fp32 -> (1024,96) fp16, zeros at pad slots ----
// Single-term fp16 (10-bit mantissa): dot error ~ sqrt(76)*2^-11 ~ 0.02 abs --
// BETTER than the previous 2-term bf16 split, at HALF the MFMA count.
__global__ __launch_bounds__(256)
void prepack_w(const float* __restrict__ w, _Float16* __restrict__ wf)
{
    int idx = blockIdx.x * 256 + threadIdx.x;
    if (idx >= NEXT * KSLOT) return;
    int fe = idx / KSLOT;
    int t  = idx - fe * KSLOT;
    int kk = t >> 2;
    int c  = t & 3;
    int f      = fe >> 1;
    int strand = fe & 1;
    float v = 0.0f;
    if (kk < 19)
        v = strand ? w[f*76 + (3-c)*19 + (18-kk)]   // reverse-complement
                   : w[f*76 + c*19 + kk];
    wf[idx] = (_Float16)v;
}

// 16B B-fragment as two naturally-8B-aligned ds_read_b64 (conflict-free, R14)
#define LDB(EO) __extension__ ({                                         \
    f16x4 p0_ = *(const f16x4*)(H + (EO));                               \
    f16x4 p1_ = *(const f16x4*)(H + (EO) + 4);                           \
    __builtin_shufflevector(p0_, p1_, 0,1,2,3,4,5,6,7); })

// ---- main: single-term fp16 GEMM, 16x16x32 (R16 structure, MFMA count halved)
// Per iter (2 pos-tiles = 32 pos): 5 shared B-frags (tile0: g0-g2, tile1:
// g2-g4) feed 12 MFMAs in 4 independent dep-3 chains.
// block = 4 waves x 32 f_ext; grid = (128,8) = 4 blocks/CU.
__global__ __launch_bounds__(256)
void pwm_mfma(const float* __restrict__ x,
              const _Float16* __restrict__ wf,
              float* __restrict__ out)
{
    __shared__ __align__(16) _Float16 H[4096];   // fp16(x), [pos][c], tail 0
    __shared__ float red[128];

    const int tid   = threadIdx.x;
    const int b     = blockIdx.x;
    const int ftile = blockIdx.y;   // 0..7 (128 f_ext per block)
    const int lane  = tid & 63;
    const int wave  = tid >> 6;
    const int row   = lane & 15;    // position within 16-tile / W k-row
    const int g     = lane >> 4;    // k-eighth group (0..3)

    // stage fp16(x[b]) position-major [pos][c]; 8B LDS writes, tail zeroed
    for (int i = tid; i < 1024; i += 256) {
        f16x4 hv;
        #pragma unroll
        for (int c = 0; c < 4; ++c) {
            float v = (i < LEN) ? x[(size_t)b*4000 + c*1000 + i] : 0.0f;
            hv[c] = (_Float16)v;
        }
        *(f16x4*)(H + i*4) = hv;
    }

    // A fragments (W fp16) -> regs: lane holds W[f0+fg*16+row][k = s*32 + g*8 + j]
    f16x8 wa[2][3];
    {
        const int f0 = ftile*128 + wave*32;
        #pragma unroll
        for (int fg = 0; fg < 2; ++fg)
            #pragma unroll
            for (int s = 0; s < 3; ++s) {
                const size_t o = (size_t)(f0 + fg*16 + row)*KSLOT + s*32 + g*8;
                wa[fg][s] = *(const f16x8*)(wf + o);
            }
    }
    __syncthreads();

    // B element base: slot k = s*32 + g*8 + j -> x element (it*32 + row + s*8 + g*2)*4
    const int base = row*4 + g*8;
    const f32x4 zc = {};

    float m0[4], m1[4];
    #pragma unroll
    for (int r = 0; r < 4; ++r) { m0[r] = -INFINITY; m1[r] = -INFINITY; }

    for (int it = 0; it < 31; ++it) {
        const int o_ = it*128 + base;
        f16x8 g0 = LDB(o_);
        f16x8 g1 = LDB(o_ + 32);
        f16x8 g2 = LDB(o_ + 64);    // shared: tile0 s2 / tile1 s0
        f16x8 g3 = LDB(o_ + 96);
        f16x8 g4 = LDB(o_ + 128);

        // 4 independent dep-3 chains (2 filter-tiles x 2 pos-tiles), 12 MFMAs
        f32x4 a00 = MFMA16(wa[0][0], g0, zc);
        f32x4 a10 = MFMA16(wa[1][0], g0, zc);
        f32x4 a01 = MFMA16(wa[0][0], g2, zc);
        f32x4 a11 = MFMA16(wa[1][0], g2, zc);
        a00 = MFMA16(wa[0][1], g1, a00);
        a10 = MFMA16(wa[1][1], g1, a10);
        a01 = MFMA16(wa[0][1], g3, a01);
        a11 = MFMA16(wa[1][1], g3, a11);
        a00 = MFMA16(wa[0][2], g2, a00);
        a10 = MFMA16(wa[1][2], g2, a10);
        a01 = MFMA16(wa[0][2], g4, a01);
        a11 = MFMA16(wa[1][2], g4, a11);

        if (it == 30 && row >= 6) {   // tile1 pos = 976+row >= 982: exclude
            #pragma unroll
            for (int r = 0; r < 4; ++r) { a01[r] = -INFINITY; a11[r] = -INFINITY; }
        }
        #pragma unroll
        for (int r = 0; r < 4; ++r) {
            m0[r] = fmaxf(m0[r], fmaxf(a00[r], a01[r]));
            m1[r] = fmaxf(m1[r], fmaxf(a10[r], a11[r]));
        }
    }

    // reduce over the 16 position-columns (lane&15)
    #pragma unroll
    for (int off = 1; off < 16; off <<= 1)
        #pragma unroll
        for (int r = 0; r < 4; ++r) {
            m0[r] = fmaxf(m0[r], __shfl_xor(m0[r], off, 64));
            m1[r] = fmaxf(m1[r], __shfl_xor(m1[r], off, 64));
        }

    // D row (filter within 16-tile) = g*4 + r
    if (row == 0) {
        #pragma unroll
        for (int r = 0; r < 4; ++r) {
            red[wave*32 +      g*4 + r] = m0[r];
            red[wave*32 + 16 + g*4 + r] = m1[r];
        }
    }
    __syncthreads();
    if (tid < 64)   // combine strand pairs (f_ext = 2f, 2f+1)
        out[(size_t)b*NPWM + ftile*64 + tid] = fmaxf(red[2*tid], red[2*tid+1]);
}

extern "C" void kernel_launch(void* const* d_in, const int* in_sizes, int n_in,
                              void* d_out, int out_size, void* d_ws, size_t ws_size,
                              hipStream_t stream)
{
    const float* x = (const float*)d_in[0];   // (128, 4, 1000)
    const float* w = (const float*)d_in[1];   // (512, 4, 19)
    float* out = (float*)d_out;               // (128, 512)

    _Float16* wf = (_Float16*)d_ws;           // 1024*96 fp16

    prepack_w<<<dim3((NEXT*KSLOT + 255)/256), 256, 0, stream>>>(w, wf);
    pwm_mfma<<<dim3(BATCH, 8), 256, 0, stream>>>(x, wf, out);
}

// Round 20
// 31.088 us; speedup vs baseline: 3.4893x; 1.0784x over previous
//
#include <hip/hip_runtime.h>
#include <math.h>

#define BATCH 128
#define NPWM 512
#define LEN 1000
#define NEXT 1024     // 2*NPWM (fwd + revcomp interleaved: f_ext = 2*f + strand)
#define KSLOT 96      // kk padded 19->24, slot = kk*4 + c (16x16x32: K mult of 32)

typedef _Float16 f16x4 __attribute__((ext_vector_type(4)));
typedef _Float16 f16x8 __attribute__((ext_vector_type(8)));
typedef float    f32x4 __attribute__((ext_vector_type(4)));

#define MFMA16(a, b, c) __builtin_amdgcn_mfma_f32_16x16x32_f16(a, b, c, 0, 0, 0)

// ---- prepack W: (512,4,19) fp32 -> (1024,96) fp16, zeros at pad slots ----
__global__ __launch_bounds__(256)
void prepack_w(const float* __restrict__ w, _Float16* __restrict__ wf)
{
    int idx = blockIdx.x * 256 + threadIdx.x;
    if (idx >= NEXT * KSLOT) return;
    int fe = idx / KSLOT;
    int t  = idx - fe * KSLOT;
    int kk = t >> 2;
    int c  = t & 3;
    int f      = fe >> 1;
    int strand = fe & 1;
    float v = 0.0f;
    if (kk < 19)
        v = strand ? w[f*76 + (3-c)*19 + (18-kk)]   // reverse-complement
                   : w[f*76 + c*19 + kk];
    wf[idx] = (_Float16)v;
}

// 16B B-fragment as two naturally-8B-aligned ds_read_b64 (conflict-free, R14)
#define LDB(EO) __extension__ ({                                         \
    f16x4 p0_ = *(const f16x4*)(H + (EO));                               \
    f16x4 p1_ = *(const f16x4*)(H + (EO) + 4);                           \
    __builtin_shufflevector(p0_, p1_, 0,1,2,3,4,5,6,7); })

// ---- main: single-term fp16 GEMM, 16x16x32, fg=4 (LDS-amortized).
// block = 4 waves = 2 filter-halves(64 f_ext, 4 tiles) x 2 position-halves.
// Per iter (2 pos-tiles = 32 pos): 5 shared B-frags (10 ds_read_b64) feed
// 24 MFMAs in 8 independent dep-3 chains; B loads just-in-time so <=4 frags
// live (VGPR budget: A 48 + acc 32 + m 16 + B ~16 + addr ~12 <= 128 ->
// 4 waves/SIMD). grid = (128,8) = 4 blocks/CU.
__global__ __launch_bounds__(256, 4)
void pwm_mfma(const float* __restrict__ x,
              const _Float16* __restrict__ wf,
              float* __restrict__ out)
{
    __shared__ __align__(16) _Float16 H[4096];   // fp16(x), [pos][c], tail 0
    __shared__ float red[2][128];

    const int tid   = threadIdx.x;
    const int b     = blockIdx.x;
    const int ftile = blockIdx.y;   // 0..7 (128 f_ext per block)
    const int lane  = tid & 63;
    const int wave  = tid >> 6;
    const int fhalf = wave & 1;     // which 64 f_ext
    const int wp    = wave >> 1;    // position half
    const int row   = lane & 15;    // position within 16-tile / W k-row
    const int g     = lane >> 4;    // k-eighth group (0..3)

    // stage fp16(x[b]) position-major [pos][c]; 8B LDS writes, tail zeroed
    for (int i = tid; i < 1024; i += 256) {
        f16x4 hv;
        #pragma unroll
        for (int c = 0; c < 4; ++c) {
            float v = (i < LEN) ? x[(size_t)b*4000 + c*1000 + i] : 0.0f;
            hv[c] = (_Float16)v;
        }
        *(f16x4*)(H + i*4) = hv;
    }

    // A fragments (W fp16) -> regs: lane holds W[f0+fg*16+row][k = s*32 + g*8 + j]
    f16x8 wa[4][3];
    {
        const int f0 = ftile*128 + fhalf*64;
        #pragma unroll
        for (int fg = 0; fg < 4; ++fg)
            #pragma unroll
            for (int s = 0; s < 3; ++s) {
                const size_t o = (size_t)(f0 + fg*16 + row)*KSLOT + s*32 + g*8;
                wa[fg][s] = *(const f16x8*)(wf + o);
            }
    }
    __syncthreads();

    // B element base: slot k = s*32 + g*8 + j -> x element (it*32 + row + s*8 + g*2)*4
    const int base = row*4 + g*8;
    const f32x4 zc = {};

    float m[4][4];
    #pragma unroll
    for (int fg = 0; fg < 4; ++fg)
        #pragma unroll
        for (int r = 0; r < 4; ++r) m[fg][r] = -INFINITY;

    const int it_beg = wp ? 16 : 0;
    const int it_end = wp ? 31 : 16;
    for (int it = it_beg; it < it_end; ++it) {
        const int o_ = it*128 + base;
        f32x4 a0[4], a1[4];

        // just-in-time B loads; 8 independent dep-3 chains
        f16x8 g0 = LDB(o_);
        f16x8 g2 = LDB(o_ + 64);     // shared: tile0 s2 / tile1 s0
        #pragma unroll
        for (int fg = 0; fg < 4; ++fg) a0[fg] = MFMA16(wa[fg][0], g0, zc);
        #pragma unroll
        for (int fg = 0; fg < 4; ++fg) a1[fg] = MFMA16(wa[fg][0], g2, zc);
        f16x8 g1 = LDB(o_ + 32);
        #pragma unroll
        for (int fg = 0; fg < 4; ++fg) a0[fg] = MFMA16(wa[fg][1], g1, a0[fg]);
        f16x8 g3 = LDB(o_ + 96);
        #pragma unroll
        for (int fg = 0; fg < 4; ++fg) a1[fg] = MFMA16(wa[fg][1], g3, a1[fg]);
        #pragma unroll
        for (int fg = 0; fg < 4; ++fg) a0[fg] = MFMA16(wa[fg][2], g2, a0[fg]);
        f16x8 g4 = LDB(o_ + 128);
        #pragma unroll
        for (int fg = 0; fg < 4; ++fg) a1[fg] = MFMA16(wa[fg][2], g4, a1[fg]);

        if (it == 30 && row >= 6) {   // tile1 pos = 976+row >= 982: exclude
            #pragma unroll
            for (int fg = 0; fg < 4; ++fg)
                #pragma unroll
                for (int r = 0; r < 4; ++r) a1[fg][r] = -INFINITY;
        }
        #pragma unroll
        for (int fg = 0; fg < 4; ++fg)
            #pragma unroll
            for (int r = 0; r < 4; ++r)
                m[fg][r] = fmaxf(m[fg][r], fmaxf(a0[fg][r], a1[fg][r]));
    }

    // reduce over the 16 position-columns (lane&15)
    #pragma unroll
    for (int off = 1; off < 16; off <<= 1)
        #pragma unroll
        for (int fg = 0; fg < 4; ++fg)
            #pragma unroll
            for (int r = 0; r < 4; ++r)
                m[fg][r] = fmaxf(m[fg][r], __shfl_xor(m[fg][r], off, 64));

    // D row (filter within 16-tile) = g*4 + r
    if (row == 0) {
        #pragma unroll
        for (int fg = 0; fg < 4; ++fg)
            #pragma unroll
            for (int r = 0; r < 4; ++r)
                red[wp][fhalf*64 + fg*16 + g*4 + r] = m[fg][r];
    }
    __syncthreads();
    if (tid < 64) {   // combine strand pairs (f_ext = 2f, 2f+1) and position halves
        float v0 = fmaxf(red[0][2*tid], red[0][2*tid+1]);
        float v1 = fmaxf(red[1][2*tid], red[1][2*tid+1]);
        out[(size_t)b*NPWM + ftile*64 + tid] = fmaxf(v0, v1);
    }
}

extern "C" void kernel_launch(void* const* d_in, const int* in_sizes, int n_in,
                              void* d_out, int out_size, void* d_ws, size_t ws_size,
                              hipStream_t stream)
{
    const float* x = (const float*)d_in[0];   // (128, 4, 1000)
    const float* w = (const float*)d_in[1];   // (512, 4, 19)
    float* out = (float*)d_out;               // (128, 512)

    _Float16* wf = (_Float16*)d_ws;           // 1024*96 fp16

    prepack_w<<<dim3((NEXT*KSLOT + 255)/256), 256, 0, stream>>>(w, wf);
    pwm_mfma<<<dim3(BATCH, 8), 256, 0, stream>>>(x, wf, out);
}

// Round 21
// 30.703 us; speedup vs baseline: 3.5331x; 1.0125x over previous
//
#include <hip/hip_runtime.h>
#include <math.h>

#define BATCH 128
#define NPWM 512
#define LEN 1000
#define NEXT 1024     // 2*NPWM (fwd + revcomp interleaved: f_ext = 2*f + strand)
#define KSLOT 80      // kk padded 19->20, slot = kk*4 + c; K chunks 32+32+16

typedef _Float16 f16x4 __attribute__((ext_vector_type(4)));
typedef _Float16 f16x8 __attribute__((ext_vector_type(8)));
typedef float    f32x4 __attribute__((ext_vector_type(4)));

#define MFMAK32(a, b, c) __builtin_amdgcn_mfma_f32_16x16x32_f16(a, b, c, 0, 0, 0)
#define MFMAK16(a, b, c) __builtin_amdgcn_mfma_f32_16x16x16f16(a, b, c, 0, 0, 0)

// ---- prepack W: (512,4,19) fp32 -> (1024,80) fp16, zeros at pad slots ----
__global__ __launch_bounds__(256)
void prepack_w(const float* __restrict__ w, _Float16* __restrict__ wf)
{
    int idx = blockIdx.x * 256 + threadIdx.x;
    if (idx >= NEXT * KSLOT) return;
    int fe = idx / KSLOT;
    int t  = idx - fe * KSLOT;
    int kk = t >> 2;
    int c  = t & 3;
    int f      = fe >> 1;
    int strand = fe & 1;
    float v = 0.0f;
    if (kk < 19)
        v = strand ? w[f*76 + (3-c)*19 + (18-kk)]   // reverse-complement
                   : w[f*76 + c*19 + kk];
    wf[idx] = (_Float16)v;
}

// 16B B-fragment as two naturally-8B-aligned ds_read_b64 (conflict-free, R14)
#define LDB(EO) __extension__ ({                                         \
    f16x4 p0_ = *(const f16x4*)(H + (EO));                               \
    f16x4 p1_ = *(const f16x4*)(H + (EO) + 4);                           \
    __builtin_shufflevector(p0_, p1_, 0,1,2,3,4,5,6,7); })

// ---- main: single-term fp16 GEMM, mixed-shape K=80 (32+32+16), fg=4.
// block = 4 waves = 2 filter-halves(64 f_ext) x 2 position-halves.
// Per iter (2 pos-tiles = 32 pos): 10 x 8B LDS reads feed 20 MFMAs
// (4fg x 2tiles x {K32,K32,K16}) in 8 independent dep-3 chains.
// K padding now 4/80 slots (was 20/96): -17% MFMA work vs R20.
// grid = (128,8) = 4 blocks/CU; VGPR ~115 -> 4 waves/SIMD.
__global__ __launch_bounds__(256, 4)
void pwm_mfma(const float* __restrict__ x,
              const _Float16* __restrict__ wf,
              float* __restrict__ out)
{
    __shared__ __align__(16) _Float16 H[4096];   // fp16(x), [pos][c], tail 0
    __shared__ float red[2][128];

    const int tid   = threadIdx.x;
    const int b     = blockIdx.x;
    const int ftile = blockIdx.y;   // 0..7 (128 f_ext per block)
    const int lane  = tid & 63;
    const int wave  = tid >> 6;
    const int fhalf = wave & 1;     // which 64 f_ext
    const int wp    = wave >> 1;    // position half
    const int row   = lane & 15;    // position within 16-tile / W k-row
    const int g     = lane >> 4;    // k-group (0..3)

    // stage fp16(x[b]) position-major [pos][c]; 8B LDS writes, tail zeroed
    for (int i = tid; i < 1024; i += 256) {
        f16x4 hv;
        #pragma unroll
        for (int c = 0; c < 4; ++c) {
            float v = (i < LEN) ? x[(size_t)b*4000 + c*1000 + i] : 0.0f;
            hv[c] = (_Float16)v;
        }
        *(f16x4*)(H + i*4) = hv;
    }

    // A fragments -> regs.
    // K32 chunks s=0,1: lane holds W[f][k = s*32 + g*8 + j], j=0..7 (f16x8).
    // K16 chunk: lane holds W[f][k = 64 + g*4 + j], j=0..3 (f16x4).
    f16x8 wa[4][2];
    f16x4 wa2[4];
    {
        const int f0 = ftile*128 + fhalf*64;
        #pragma unroll
        for (int fg = 0; fg < 4; ++fg) {
            const size_t fo = (size_t)(f0 + fg*16 + row)*KSLOT;
            #pragma unroll
            for (int s = 0; s < 2; ++s)
                wa[fg][s] = *(const f16x8*)(wf + fo + s*32 + g*8);
            wa2[fg] = *(const f16x4*)(wf + fo + 64 + g*4);
        }
    }
    __syncthreads();

    // B addressing (tile0 pos p = it*32 + row; tile1 = +16):
    //  K32 s: slot k = s*32+g*8+j -> x elem (p + s*8 + g*2)*4 ... 8 consecutive
    //  K16  : slot k = 64+g*4+j   -> x elem (p + 16 + g)*4   ... 4 consecutive
    //  (K16 lanes with equal row+g read the same 8B -> broadcast / 2-way max)
    const int base = row*4 + g*8;
    const f32x4 zc = {};

    float m[4][4];
    #pragma unroll
    for (int fg = 0; fg < 4; ++fg)
        #pragma unroll
        for (int r = 0; r < 4; ++r) m[fg][r] = -INFINITY;

    const int it_beg = wp ? 16 : 0;
    const int it_end = wp ? 31 : 16;
    for (int it = it_beg; it < it_end; ++it) {
        const int o_ = it*128 + base;
        f32x4 a0[4], a1[4];

        f16x8 g00 = LDB(o_);          // tile0 s0
        f16x8 g10 = LDB(o_ + 64);     // tile1 s0
        #pragma unroll
        for (int fg = 0; fg < 4; ++fg) a0[fg] = MFMAK32(wa[fg][0], g00, zc);
        #pragma unroll
        for (int fg = 0; fg < 4; ++fg) a1[fg] = MFMAK32(wa[fg][0], g10, zc);

        f16x8 g01 = LDB(o_ + 32);     // tile0 s1
        #pragma unroll
        for (int fg = 0; fg < 4; ++fg) a0[fg] = MFMAK32(wa[fg][1], g01, a0[fg]);
        f16x8 g11 = LDB(o_ + 96);     // tile1 s1
        #pragma unroll
        for (int fg = 0; fg < 4; ++fg) a1[fg] = MFMAK32(wa[fg][1], g11, a1[fg]);

        f16x4 b20 = *(const f16x4*)(H + it*128 + (row + 16 + g)*4);  // tile0 K16
        #pragma unroll
        for (int fg = 0; fg < 4; ++fg) a0[fg] = MFMAK16(wa2[fg], b20, a0[fg]);
        f16x4 b21 = *(const f16x4*)(H + it*128 + (row + 32 + g)*4);  // tile1 K16
        #pragma unroll
        for (int fg = 0; fg < 4; ++fg) a1[fg] = MFMAK16(wa2[fg], b21, a1[fg]);

        if (it == 30 && row >= 6) {   // tile1 pos = 976+row >= 982: exclude
            #pragma unroll
            for (int fg = 0; fg < 4; ++fg)
                #pragma unroll
                for (int r = 0; r < 4; ++r) a1[fg][r] = -INFINITY;
        }
        #pragma unroll
        for (int fg = 0; fg < 4; ++fg)
            #pragma unroll
            for (int r = 0; r < 4; ++r)
                m[fg][r] = fmaxf(m[fg][r], fmaxf(a0[fg][r], a1[fg][r]));
    }

    // reduce over the 16 position-columns (lane&15)
    #pragma unroll
    for (int off = 1; off < 16; off <<= 1)
        #pragma unroll
        for (int fg = 0; fg < 4; ++fg)
            #pragma unroll
            for (int r = 0; r < 4; ++r)
                m[fg][r] = fmaxf(m[fg][r], __shfl_xor(m[fg][r], off, 64));

    // D row (filter within 16-tile) = g*4 + r
    if (row == 0) {
        #pragma unroll
        for (int fg = 0; fg < 4; ++fg)
            #pragma unroll
            for (int r = 0; r < 4; ++r)
                red[wp][fhalf*64 + fg*16 + g*4 + r] = m[fg][r];
    }
    __syncthreads();
    if (tid < 64) {   // combine strand pairs (f_ext = 2f, 2f+1) and position halves
        float v0 = fmaxf(red[0][2*tid], red[0][2*tid+1]);
        float v1 = fmaxf(red[1][2*tid], red[1][2*tid+1]);
        out[(size_t)b*NPWM + ftile*64 + tid] = fmaxf(v0, v1);
    }
}

extern "C" void kernel_launch(void* const* d_in, const int* in_sizes, int n_in,
                              void* d_out, int out_size, void* d_ws, size_t ws_size,
                              hipStream_t stream)
{
    const float* x = (const float*)d_in[0];   // (128, 4, 1000)
    const float* w = (const float*)d_in[1];   // (512, 4, 19)
    float* out = (float*)d_out;               // (128, 512)

    _Float16* wf = (_Float16*)d_ws;           // 1024*80 fp16

    prepack_w<<<dim3((NEXT*KSLOT + 255)/256), 256, 0, stream>>>(w, wf);
    pwm_mfma<<<dim3(BATCH, 8), 256, 0, stream>>>(x, wf, out);
}